// Round 10
// baseline (541.990 us; speedup 1.0000x reference)
//
#include <hip/hip_runtime.h>
#include <hip/hip_bf16.h>

#define B_  32
#define T_  1024
#define C_  8
#define K_  10
#define LH_ 32

// ---------------------------------------------------------------------------
// workspace layout (floats)
// ---------------------------------------------------------------------------
#define WS_H    0
#define WS_SQ   1048576            // B*T*32
#define WS_ACC  (WS_SQ + 32768)
#define WS_WT   (WS_ACC + 1024)   // transposed weights, 106496 floats
#define WS_Y    (WS_WT + 106496)  // [B][128]

// transposed-weight segment offsets (k-major, coalesced in o)
#define WT_C1_0 0
#define WT_C2_0 768
#define WT_DW0  3840
#define WT_C1_1 4096
#define WT_C2_1 10240
#define WT_DW1  22528
#define WT_C1_2 24576
#define WT_C2_2 49152
#define WT_DW2  98304
#define WT_TOTAL 106496

#define PROJ_BLOCKS ((B_ * T_ * LH_) / 256)      // 4096
#define WT_BLOCKS   ((WT_TOTAL + 255) / 256)     // 416

struct WSegs { const float* src[9]; int k3[9]; int colog2[9]; int off[10]; };

// ---------------------------------------------------------------------------
// K1: h = x @ pw + pb (fp32), sq = ||h||^2, zero acc.
// Blocks >= PROJ_BLOCKS transpose conv weights into wT.
// ---------------------------------------------------------------------------
__global__ __launch_bounds__(256) void k_project(
    const float* __restrict__ x,
    const float* __restrict__ pw,
    const float* __restrict__ pb,
    float* __restrict__ h, float* __restrict__ sq, float* __restrict__ acc,
    WSegs S, float* __restrict__ wT)
{
    if (blockIdx.x >= PROJ_BLOCKS) {
        int gid = (blockIdx.x - PROJ_BLOCKS) * 256 + threadIdx.x;
        if (gid < WT_TOTAL) {
#pragma unroll
            for (int s = 0; s < 9; ++s) {
                if (gid >= S.off[s] && gid < S.off[s + 1]) {
                    int local = gid - S.off[s];
                    int k = local >> S.colog2[s];
                    int o = local & ((1 << S.colog2[s]) - 1);
                    wT[gid] = S.src[s][o * S.k3[s] + k];
                }
            }
        }
        return;
    }

    int gid = blockIdx.x * 256 + threadIdx.x;
    if (gid < B_ * LH_) acc[gid] = 0.f;
    int row = gid >> 5;
    int i   = gid & 31;
    const float* xr = x + (size_t)row * C_;
    float4 x0 = *(const float4*)xr;
    float4 x1 = *(const float4*)(xr + 4);
    float hv = pb[i];
    hv = fmaf(x0.x, pw[0 * LH_ + i], hv);
    hv = fmaf(x0.y, pw[1 * LH_ + i], hv);
    hv = fmaf(x0.z, pw[2 * LH_ + i], hv);
    hv = fmaf(x0.w, pw[3 * LH_ + i], hv);
    hv = fmaf(x1.x, pw[4 * LH_ + i], hv);
    hv = fmaf(x1.y, pw[5 * LH_ + i], hv);
    hv = fmaf(x1.z, pw[6 * LH_ + i], hv);
    hv = fmaf(x1.w, pw[7 * LH_ + i], hv);
    h[(size_t)row * LH_ + i] = hv;
    float e = hv * hv;
#pragma unroll
    for (int off = 1; off < 32; off <<= 1) e += __shfl_xor(e, off, 64);
    if (i == 0) sq[row] = e;
}

// ---------------------------------------------------------------------------
// DPP full-wave min (u32) — verified correct on HW.
// ---------------------------------------------------------------------------
__device__ __forceinline__ unsigned wave_min_u32(unsigned v)
{
#define DPP_MIN(ctrl) \
    v = min(v, (unsigned)__builtin_amdgcn_update_dpp((int)v, (int)v, ctrl, 0xF, 0xF, false))
    DPP_MIN(0x111);  // row_shr:1
    DPP_MIN(0x112);  // row_shr:2
    DPP_MIN(0x114);  // row_shr:4
    DPP_MIN(0x118);  // row_shr:8
    DPP_MIN(0x142);  // row_bcast:15
    DPP_MIN(0x143);  // row_bcast:31
#undef DPP_MIN
    return (unsigned)__builtin_amdgcn_readlane((int)v, 63);
}

// ---------------------------------------------------------------------------
// Fused TCN (proven R3 math, R5 lifetime-overlapped layout; peak 4032
// floats <= the 4608-float laplace tile). Every region reuse crosses an
// existing __syncthreads (no WAR hazard). Verified passing in R5 run.
// ---------------------------------------------------------------------------
struct TcnW {
    const float *x;
    const float *c1b0, *c2b0, *db0;
    const float *c1b1, *c2b1, *db1;
    const float *c1b2, *c2b2, *db2;
};

__device__ void tcn_block(int b, const TcnW& W, const float* __restrict__ wT,
                          float* sm, float* y, int tid)
{
    float* xw = sm + 0;      // 232   x rows 995..1023
    float* a0 = sm + 232;    // 864
    float* o0 = sm + 3232;   // 800
    float* a1 = sm + 0;      // 1344 (xw,a0 dead)
    float* o1 = sm + 1344;   // 1088
    float* a2 = sm + 0;      // 1152 (a1 dead)

    if (tid < 232) xw[tid] = W.x[(size_t)b * (T_ * C_) + 995 * C_ + tid];
    __syncthreads();

    // conv1_0: 27x32, CI=8, DIL=1
#pragma unroll 1
    for (int e = tid; e < 27 * 32; e += 256) {
        int r = e >> 5, o = e & 31;
        const float* wr = wT + WT_C1_0;
        float s = W.c1b0[o];
#pragma unroll
        for (int i = 0; i < 8; ++i)
#pragma unroll
            for (int j = 0; j < 3; ++j)
                s = fmaf(wr[(i * 3 + j) * 32 + o], xw[(r + j) * 8 + i], s);
        a0[e] = fmaxf(s, 0.f);
    }
    __syncthreads();

    // convres_0: 25x32
#pragma unroll 1
    for (int e = tid; e < 25 * 32; e += 256) {
        int r = e >> 5, o = e & 31;
        const float* wr = wT + WT_C2_0;
        float s = W.c2b0[o];
#pragma unroll 4
        for (int i = 0; i < 32; ++i)
#pragma unroll
            for (int j = 0; j < 3; ++j)
                s = fmaf(wr[(i * 3 + j) * 32 + o], a0[(r + j) * 32 + i], s);
        s = fmaxf(s, 0.f);
        const float* dr = wT + WT_DW0;
        float rs = W.db0[o];
#pragma unroll
        for (int i = 0; i < 8; ++i)
            rs = fmaf(dr[i * 32 + o], xw[(4 + r) * 8 + i], rs);
        o0[e] = fmaxf(s + rs, 0.f);
    }
    __syncthreads();

    // conv1_1: 21x64, CI=32, DIL=2  (writes a1 over dead xw+a0)
#pragma unroll 1
    for (int e = tid; e < 21 * 64; e += 256) {
        int r = e >> 6, o = e & 63;
        const float* wr = wT + WT_C1_1;
        float s = W.c1b1[o];
#pragma unroll 4
        for (int i = 0; i < 32; ++i)
#pragma unroll
            for (int j = 0; j < 3; ++j)
                s = fmaf(wr[(i * 3 + j) * 64 + o], o0[(r + 2 * j) * 32 + i], s);
        a1[e] = fmaxf(s, 0.f);
    }
    __syncthreads();

    // convres_1: 17x64  (reads a1 + o0; writes o1)
#pragma unroll 1
    for (int e = tid; e < 17 * 64; e += 256) {
        int r = e >> 6, o = e & 63;
        const float* wr = wT + WT_C2_1;
        float s = W.c2b1[o];
#pragma unroll 4
        for (int i = 0; i < 64; ++i)
#pragma unroll
            for (int j = 0; j < 3; ++j)
                s = fmaf(wr[(i * 3 + j) * 64 + o], a1[(r + 2 * j) * 64 + i], s);
        s = fmaxf(s, 0.f);
        const float* dr = wT + WT_DW1;
        float rs = W.db1[o];
#pragma unroll 4
        for (int i = 0; i < 32; ++i)
            rs = fmaf(dr[i * 64 + o], o0[(8 + r) * 32 + i], rs);
        o1[e] = fmaxf(s + rs, 0.f);
    }
    __syncthreads();

    // conv1_2: 9x128, CI=64, DIL=4  (writes a2 over dead a1)
#pragma unroll 1
    for (int e = tid; e < 9 * 128; e += 256) {
        int r = e >> 7, o = e & 127;
        const float* wr = wT + WT_C1_2;
        float s = W.c1b2[o];
#pragma unroll 4
        for (int i = 0; i < 64; ++i)
#pragma unroll
            for (int j = 0; j < 3; ++j)
                s = fmaf(wr[(i * 3 + j) * 128 + o], o1[(r + 4 * j) * 64 + i], s);
        a2[e] = fmaxf(s, 0.f);
    }
    __syncthreads();

    // convres_2: 1x128
    if (tid < 128) {
        int o = tid;
        const float* wr = wT + WT_C2_2;
        float s = W.c2b2[o];
#pragma unroll 4
        for (int i = 0; i < 128; ++i)
#pragma unroll
            for (int j = 0; j < 3; ++j)
                s = fmaf(wr[(i * 3 + j) * 128 + o], a2[(4 * j) * 128 + i], s);
        s = fmaxf(s, 0.f);
        const float* dr = wT + WT_DW2;
        float rs = W.db2[o];
#pragma unroll 4
        for (int i = 0; i < 64; ++i)
            rs = fmaf(dr[i * 128 + o], o1[16 * 64 + i], rs);
        y[(size_t)b * 128 + o] = fmaxf(s + rs, 0.f);
    }
}

// ---------------------------------------------------------------------------
// K2: Laplace + 32 leading TCN blocks hidden in its shadow.
// R10: R5's STILE-64 double-buffer geometry (LDS 19968 B -> 8 blocks/CU)
// combined with __launch_bounds__(256, 8) forcing VGPR <= 64 (R5 failed
// only because VGPR drifted to 72, halving waves/SIMD at the 64-cliff;
// R9 proved 64-VGPR-with-spill costs <5us). First config where BOTH the
// LDS cap (8 blocks/CU) and VGPR cap (8 waves/SIMD) allow 32 waves/CU —
// double R4/R9's residency. Math/keys/selection bit-identical to R4-R9.
// ---------------------------------------------------------------------------
#define STILE 64
#define SPAD  36
#define TCN_BLOCKS 32
#define NTILE (T_ / STILE)   // 16

__global__ __launch_bounds__(256, 8) void k_laplace(
    const float* __restrict__ h, const float* __restrict__ sq,
    float* __restrict__ acc, TcnW tw, const float* __restrict__ wT,
    float* __restrict__ y)
{
    __shared__ float tile[2][STILE * SPAD];   // 18432 B double buffer
    __shared__ float wacc[4 * 32];
    __shared__ float qbuf[8 * 32];

    if (blockIdx.x < TCN_BLOCKS) {
        tcn_block(blockIdx.x, tw, wT, &tile[0][0], y, threadIdx.x);
        return;
    }
    const int bid = blockIdx.x - TCN_BLOCKS;

    const int tid = threadIdx.x;
    const int wv  = tid >> 6;
    const int ln  = tid & 63;
    const int b   = bid >> 7;
    const int t0  = (bid & 127) * 8;
    const int tA  = t0 + wv * 2;
    const int tB  = tA + 1;

    const float* hb  = h  + (size_t)b * T_ * LH_;
    const float* sqb = sq + b * T_;

    if (ln < 32) {
        qbuf[(wv * 2 + 0) * 32 + ln] = hb[tA * LH_ + ln];
        qbuf[(wv * 2 + 1) * 32 + ln] = hb[tB * LH_ + ln];
    }
    float qA[32], qB[32];
#pragma unroll
    for (int i4 = 0; i4 < 8; ++i4) {
        float4 a4 = *(const float4*)(hb + (size_t)tA * LH_ + i4 * 4);
        float4 b4 = *(const float4*)(hb + (size_t)tB * LH_ + i4 * 4);
        qA[i4 * 4 + 0] = a4.x; qA[i4 * 4 + 1] = a4.y;
        qA[i4 * 4 + 2] = a4.z; qA[i4 * 4 + 3] = a4.w;
        qB[i4 * 4 + 0] = b4.x; qB[i4 * 4 + 1] = b4.y;
        qB[i4 * 4 + 2] = b4.z; qB[i4 * 4 + 3] = b4.w;
    }
    const float sqA = sqb[tA], sqB = sqb[tB];

    // stage 64 rows x 32 floats: each thread 2x float4
    const int st_r  = tid >> 3, st_c4 = tid & 7;
    auto stage = [&](int buf, int s_base) {
#pragma unroll
        for (int u = 0; u < 2; ++u) {
            int r = st_r + u * 32;
            float4 val = *(const float4*)(hb + (size_t)(s_base + r) * LH_ + st_c4 * 4);
            *(float4*)&tile[buf][r * SPAD + st_c4 * 4] = val;
        }
    };

    unsigned kA[16], kB[16];

    stage(0, 0);
    __syncthreads();

#pragma unroll
    for (int tl = 0; tl < NTILE; ++tl) {
        const int s_base = tl * STILE;
        const int cur = tl & 1;
        if (tl + 1 < NTILE) stage(cur ^ 1, s_base + STILE);
        {
            const int s  = s_base + ln;
            const float* hs = &tile[cur][ln * SPAD];
            float dA = 0.f, dB = 0.f;
#pragma unroll
            for (int q4 = 0; q4 < 8; ++q4) {
                float4 hv4 = *(const float4*)(hs + q4 * 4);
                dA = fmaf(hv4.x, qA[q4 * 4 + 0], dA); dB = fmaf(hv4.x, qB[q4 * 4 + 0], dB);
                dA = fmaf(hv4.y, qA[q4 * 4 + 1], dA); dB = fmaf(hv4.y, qB[q4 * 4 + 1], dB);
                dA = fmaf(hv4.z, qA[q4 * 4 + 2], dA); dB = fmaf(hv4.z, qB[q4 * 4 + 2], dB);
                dA = fmaf(hv4.w, qA[q4 * 4 + 3], dA); dB = fmaf(hv4.w, qB[q4 * 4 + 3], dB);
            }
            const float sqs = sqb[s];
            float d2A = fmaxf(sqA + sqs - 2.f * dA, 0.f);
            float d2B = fmaxf(sqB + sqs - 2.f * dB, 0.f);
            unsigned keyA = (__float_as_uint(d2A) & 0xFFFFFC00u) | (unsigned)s;
            unsigned keyB = (__float_as_uint(d2B) & 0xFFFFFC00u) | (unsigned)s;
            if (s == tA) keyA = 0xFFFFFC00u | (unsigned)s;
            if (s == tB) keyB = 0xFFFFFC00u | (unsigned)s;
            kA[tl] = keyA;
            kB[tl] = keyB;
        }
        __syncthreads();   // staging of nxt done; cur free for reuse next iter
    }

    float racc = 0.f;

    auto process = [&](unsigned (&ku)[16], int qslot) {
        // ---- per-lane bitonic sort, ascending (static indices) ----
#pragma unroll
        for (int k = 2; k <= 16; k <<= 1) {
#pragma unroll
            for (int j = k >> 1; j > 0; j >>= 1) {
#pragma unroll
                for (int i = 0; i < 16; ++i) {
                    int l = i ^ j;
                    if (l > i) {
                        unsigned a = ku[i], bb = ku[l];
                        unsigned mn = min(a, bb), mx = max(a, bb);
                        bool up = ((i & k) == 0);
                        ku[i] = up ? mn : mx;
                        ku[l] = up ? mx : mn;
                    }
                }
            }
        }
        // ---- pop-head extraction: K rounds; shift depth 11 sufficient ----
        int   sk[K_];
        float wk[K_];
#pragma unroll
        for (int r = 0; r < K_; ++r) {
            unsigned mu = wave_min_u32(ku[0]);
            int s_win = (int)(mu & 1023u);
            sk[r] = s_win;
            wk[r] = __expf(-0.5f * __uint_as_float(mu & 0xFFFFFC00u));
            const bool winlane = ((s_win & 63) == ln);
#pragma unroll
            for (int i = 0; i < 10; ++i)
                ku[i] = winlane ? ku[i + 1] : ku[i];
            ku[10] = winlane ? 0xFFFFFFFFu : ku[10];
        }
        const int i = ln & 31;
        const float qi = qbuf[qslot * 32 + i];
        float W = 0.f, sm = 0.f;
#pragma unroll
        for (int k = 0; k < K_; ++k) {
            W += wk[k];
            sm = fmaf(wk[k], hb[(size_t)sk[k] * LH_ + i], sm);
        }
        sm *= __builtin_amdgcn_rcpf(W + 1e-8f);
        float z  = qi - sm;
        float ex = __expf(2.f * z);
        racc += 1.f - 2.f * __builtin_amdgcn_rcpf(ex + 1.f);
    };

    process(kA, wv * 2 + 0);
    process(kB, wv * 2 + 1);

    if (ln < 32) wacc[wv * 32 + ln] = racc;
    __syncthreads();
    if (tid < 32) {
        float tot = wacc[tid] + wacc[32 + tid] + wacc[64 + tid] + wacc[96 + tid];
        atomicAdd(&acc[b * LH_ + tid], tot);
    }
}

// ---------------------------------------------------------------------------
// K3: head (unchanged, proven)
// ---------------------------------------------------------------------------
struct HeadW {
    const float *ow, *ob, *head_w, *head_b;
    const float *f1w, *f1b, *f2w, *f2b, *r1w, *r1b, *r2w, *r2b;
};

__global__ __launch_bounds__(256) void k_head(
    const float* __restrict__ y, const float* __restrict__ acc,
    HeadW hw, float* __restrict__ out)
{
    const int b = blockIdx.x, tid = threadIdx.x;
    __shared__ float yv[128], v96[96], h1[256], h2[256], h3[128];

    if (tid < 128) yv[tid] = y[b * 128 + tid];
    else if (tid < 160) {
        int j = tid - 128;
        float s = hw.ob[j];
        for (int i = 0; i < 32; ++i)
            s = fmaf(acc[b * 32 + i] * (1.f / 1024.f), hw.ow[i * 32 + j], s);
        v96[j] = s;
    }
    __syncthreads();
    if (tid < 64) {
        float s = hw.head_b[tid];
        for (int i = 0; i < 128; ++i)
            s = fmaf(yv[i], hw.head_w[i * 64 + tid], s);
        v96[32 + tid] = s;
    }
    __syncthreads();
    {
        float s = hw.f1b[tid];
        for (int i = 0; i < 96; ++i)
            s = fmaf(v96[i], hw.f1w[i * 256 + tid], s);
        h1[tid] = fmaxf(s, 0.f);
    }
    __syncthreads();
    {
        float s = hw.f2b[tid];
        for (int i = 0; i < 256; ++i)
            s = fmaf(h1[i], hw.f2w[i * 256 + tid], s);
        h2[tid] = fmaxf(s, 0.f);
    }
    __syncthreads();
    if (tid < 128) {
        float s = hw.r1b[tid];
        for (int i = 0; i < 256; ++i)
            s = fmaf(h2[i], hw.r1w[i * 128 + tid], s);
        h3[tid] = fmaxf(s, 0.f);
    }
    __syncthreads();
    if (tid < 10) {
        float s = hw.r2b[tid];
        for (int i = 0; i < 128; ++i)
            s = fmaf(h3[i], hw.r2w[i * 10 + tid], s);
        out[b * 10 + tid] = s;
    }
}

// ---------------------------------------------------------------------------
extern "C" void kernel_launch(void* const* d_in, const int* in_sizes, int n_in,
                              void* d_out, int out_size, void* d_ws, size_t ws_size,
                              hipStream_t stream)
{
    const float* x  = (const float*)d_in[0];
    const float* pw = (const float*)d_in[1];
    const float* pb = (const float*)d_in[2];

    const float* c1w0 = (const float*)d_in[5];  const float* c1b0 = (const float*)d_in[6];
    const float* c2w0 = (const float*)d_in[7];  const float* c2b0 = (const float*)d_in[8];
    const float* dw0  = (const float*)d_in[9];  const float* db0  = (const float*)d_in[10];
    const float* c1w1 = (const float*)d_in[11]; const float* c1b1 = (const float*)d_in[12];
    const float* c2w1 = (const float*)d_in[13]; const float* c2b1 = (const float*)d_in[14];
    const float* dw1  = (const float*)d_in[15]; const float* db1  = (const float*)d_in[16];
    const float* c1w2 = (const float*)d_in[17]; const float* c1b2 = (const float*)d_in[18];
    const float* c2w2 = (const float*)d_in[19]; const float* c2b2 = (const float*)d_in[20];
    const float* dw2  = (const float*)d_in[21]; const float* db2  = (const float*)d_in[22];

    TcnW tw;
    tw.x    = x;
    tw.c1b0 = c1b0; tw.c2b0 = c2b0; tw.db0 = db0;
    tw.c1b1 = c1b1; tw.c2b1 = c2b1; tw.db1 = db1;
    tw.c1b2 = c1b2; tw.c2b2 = c2b2; tw.db2 = db2;

    HeadW hw = { (const float*)d_in[3],  (const float*)d_in[4],
                 (const float*)d_in[23], (const float*)d_in[24],
                 (const float*)d_in[25], (const float*)d_in[26],
                 (const float*)d_in[27], (const float*)d_in[28],
                 (const float*)d_in[29], (const float*)d_in[30],
                 (const float*)d_in[31], (const float*)d_in[32] };

    float* W   = (float*)d_ws;
    float* h   = W + WS_H;
    float* sq  = W + WS_SQ;
    float* acc = W + WS_ACC;
    float* wT  = W + WS_WT;
    float* y   = W + WS_Y;

    WSegs S;
    const float* srcs[9] = {c1w0, c2w0, dw0, c1w1, c2w1, dw1, c1w2, c2w2, dw2};
    const int k3s[9]   = {24, 96, 8, 96, 192, 32, 192, 384, 64};
    const int col2[9]  = {5, 5, 5, 6, 6, 6, 7, 7, 7};
    const int offs[10] = {WT_C1_0, WT_C2_0, WT_DW0, WT_C1_1, WT_C2_1, WT_DW1,
                          WT_C1_2, WT_C2_2, WT_DW2, WT_TOTAL};
    for (int i = 0; i < 9; ++i) { S.src[i] = srcs[i]; S.k3[i] = k3s[i]; S.colog2[i] = col2[i]; }
    for (int i = 0; i < 10; ++i) S.off[i] = offs[i];

    k_project<<<PROJ_BLOCKS + WT_BLOCKS, 256, 0, stream>>>(x, pw, pb, h, sq, acc, S, wT);
    k_laplace<<<(B_ * T_) / 8 + TCN_BLOCKS, 256, 0, stream>>>(h, sq, acc, tw, wT, y);
    k_head<<<B_, 256, 0, stream>>>(y, acc, hw, (float*)d_out);
}

// Round 11
// 223.028 us; speedup vs baseline: 2.4301x; 2.4301x over previous
//
#include <hip/hip_runtime.h>
#include <hip/hip_bf16.h>

#define B_  32
#define T_  1024
#define C_  8
#define K_  10
#define LH_ 32

// ---------------------------------------------------------------------------
// workspace layout (floats)
// ---------------------------------------------------------------------------
#define WS_H    0
#define WS_SQ   1048576            // B*T*32
#define WS_ACC  (WS_SQ + 32768)
#define WS_WT   (WS_ACC + 1024)   // transposed weights, 106496 floats
#define WS_Y    (WS_WT + 106496)  // [B][128]

// transposed-weight segment offsets (k-major, coalesced in o)
#define WT_C1_0 0
#define WT_C2_0 768
#define WT_DW0  3840
#define WT_C1_1 4096
#define WT_C2_1 10240
#define WT_DW1  22528
#define WT_C1_2 24576
#define WT_C2_2 49152
#define WT_DW2  98304
#define WT_TOTAL 106496

#define PROJ_BLOCKS ((B_ * T_ * LH_) / 256)      // 4096
#define WT_BLOCKS   ((WT_TOTAL + 255) / 256)     // 416

struct WSegs { const float* src[9]; int k3[9]; int colog2[9]; int off[10]; };

// ---------------------------------------------------------------------------
// K1: h = x @ pw + pb (fp32), sq = ||h||^2, zero acc.
// Blocks >= PROJ_BLOCKS transpose conv weights into wT.
// ---------------------------------------------------------------------------
__global__ __launch_bounds__(256) void k_project(
    const float* __restrict__ x,
    const float* __restrict__ pw,
    const float* __restrict__ pb,
    float* __restrict__ h, float* __restrict__ sq, float* __restrict__ acc,
    WSegs S, float* __restrict__ wT)
{
    if (blockIdx.x >= PROJ_BLOCKS) {
        int gid = (blockIdx.x - PROJ_BLOCKS) * 256 + threadIdx.x;
        if (gid < WT_TOTAL) {
#pragma unroll
            for (int s = 0; s < 9; ++s) {
                if (gid >= S.off[s] && gid < S.off[s + 1]) {
                    int local = gid - S.off[s];
                    int k = local >> S.colog2[s];
                    int o = local & ((1 << S.colog2[s]) - 1);
                    wT[gid] = S.src[s][o * S.k3[s] + k];
                }
            }
        }
        return;
    }

    int gid = blockIdx.x * 256 + threadIdx.x;
    if (gid < B_ * LH_) acc[gid] = 0.f;
    int row = gid >> 5;
    int i   = gid & 31;
    const float* xr = x + (size_t)row * C_;
    float4 x0 = *(const float4*)xr;
    float4 x1 = *(const float4*)(xr + 4);
    float hv = pb[i];
    hv = fmaf(x0.x, pw[0 * LH_ + i], hv);
    hv = fmaf(x0.y, pw[1 * LH_ + i], hv);
    hv = fmaf(x0.z, pw[2 * LH_ + i], hv);
    hv = fmaf(x0.w, pw[3 * LH_ + i], hv);
    hv = fmaf(x1.x, pw[4 * LH_ + i], hv);
    hv = fmaf(x1.y, pw[5 * LH_ + i], hv);
    hv = fmaf(x1.z, pw[6 * LH_ + i], hv);
    hv = fmaf(x1.w, pw[7 * LH_ + i], hv);
    h[(size_t)row * LH_ + i] = hv;
    float e = hv * hv;
#pragma unroll
    for (int off = 1; off < 32; off <<= 1) e += __shfl_xor(e, off, 64);
    if (i == 0) sq[row] = e;
}

// ---------------------------------------------------------------------------
// DPP full-wave min (u32) — verified correct on HW.
// ---------------------------------------------------------------------------
__device__ __forceinline__ unsigned wave_min_u32(unsigned v)
{
#define DPP_MIN(ctrl) \
    v = min(v, (unsigned)__builtin_amdgcn_update_dpp((int)v, (int)v, ctrl, 0xF, 0xF, false))
    DPP_MIN(0x111);  // row_shr:1
    DPP_MIN(0x112);  // row_shr:2
    DPP_MIN(0x114);  // row_shr:4
    DPP_MIN(0x118);  // row_shr:8
    DPP_MIN(0x142);  // row_bcast:15
    DPP_MIN(0x143);  // row_bcast:31
#undef DPP_MIN
    return (unsigned)__builtin_amdgcn_readlane((int)v, 63);
}

// ---------------------------------------------------------------------------
// Fused TCN (proven R3/R4 math): one block per batch, whole chain in LDS
// (tile buffer, 9216 floats available >= 5480 needed), 256-thread strides,
// weights from wT (k-major, coalesced in o).
// ---------------------------------------------------------------------------
struct TcnW {
    const float *x;
    const float *c1b0, *c2b0, *db0;
    const float *c1b1, *c2b1, *db1;
    const float *c1b2, *c2b2, *db2;
};

__device__ void tcn_block(int b, const TcnW& W, const float* __restrict__ wT,
                          float* sm, float* y, int tid)
{
    float* xw = sm;          // 29*8  = 232   x rows 995..1023
    float* a0 = sm + 232;    // 27*32 = 864
    float* o0 = sm + 1096;   // 25*32 = 800
    float* a1 = sm + 1896;   // 21*64 = 1344
    float* o1 = sm + 3240;   // 17*64 = 1088
    float* a2 = sm + 4328;   // 9*128 = 1152  (total 5480 floats)

    if (tid < 232) xw[tid] = W.x[(size_t)b * (T_ * C_) + 995 * C_ + tid];
    __syncthreads();

    // conv1_0: 27x32, CI=8, DIL=1
#pragma unroll 1
    for (int e = tid; e < 27 * 32; e += 256) {
        int r = e >> 5, o = e & 31;
        const float* wr = wT + WT_C1_0;
        float s = W.c1b0[o];
#pragma unroll
        for (int i = 0; i < 8; ++i)
#pragma unroll
            for (int j = 0; j < 3; ++j)
                s = fmaf(wr[(i * 3 + j) * 32 + o], xw[(r + j) * 8 + i], s);
        a0[e] = fmaxf(s, 0.f);
    }
    __syncthreads();

    // convres_0: 25x32
#pragma unroll 1
    for (int e = tid; e < 25 * 32; e += 256) {
        int r = e >> 5, o = e & 31;
        const float* wr = wT + WT_C2_0;
        float s = W.c2b0[o];
#pragma unroll 4
        for (int i = 0; i < 32; ++i)
#pragma unroll
            for (int j = 0; j < 3; ++j)
                s = fmaf(wr[(i * 3 + j) * 32 + o], a0[(r + j) * 32 + i], s);
        s = fmaxf(s, 0.f);
        const float* dr = wT + WT_DW0;
        float rs = W.db0[o];
#pragma unroll
        for (int i = 0; i < 8; ++i)
            rs = fmaf(dr[i * 32 + o], xw[(4 + r) * 8 + i], rs);
        o0[e] = fmaxf(s + rs, 0.f);
    }
    __syncthreads();

    // conv1_1: 21x64, CI=32, DIL=2
#pragma unroll 1
    for (int e = tid; e < 21 * 64; e += 256) {
        int r = e >> 6, o = e & 63;
        const float* wr = wT + WT_C1_1;
        float s = W.c1b1[o];
#pragma unroll 4
        for (int i = 0; i < 32; ++i)
#pragma unroll
            for (int j = 0; j < 3; ++j)
                s = fmaf(wr[(i * 3 + j) * 64 + o], o0[(r + 2 * j) * 32 + i], s);
        a1[e] = fmaxf(s, 0.f);
    }
    __syncthreads();

    // convres_1: 17x64
#pragma unroll 1
    for (int e = tid; e < 17 * 64; e += 256) {
        int r = e >> 6, o = e & 63;
        const float* wr = wT + WT_C2_1;
        float s = W.c2b1[o];
#pragma unroll 4
        for (int i = 0; i < 64; ++i)
#pragma unroll
            for (int j = 0; j < 3; ++j)
                s = fmaf(wr[(i * 3 + j) * 64 + o], a1[(r + 2 * j) * 64 + i], s);
        s = fmaxf(s, 0.f);
        const float* dr = wT + WT_DW1;
        float rs = W.db1[o];
#pragma unroll 4
        for (int i = 0; i < 32; ++i)
            rs = fmaf(dr[i * 64 + o], o0[(8 + r) * 32 + i], rs);
        o1[e] = fmaxf(s + rs, 0.f);
    }
    __syncthreads();

    // conv1_2: 9x128, CI=64, DIL=4
#pragma unroll 1
    for (int e = tid; e < 9 * 128; e += 256) {
        int r = e >> 7, o = e & 127;
        const float* wr = wT + WT_C1_2;
        float s = W.c1b2[o];
#pragma unroll 4
        for (int i = 0; i < 64; ++i)
#pragma unroll
            for (int j = 0; j < 3; ++j)
                s = fmaf(wr[(i * 3 + j) * 128 + o], o1[(r + 4 * j) * 64 + i], s);
        a2[e] = fmaxf(s, 0.f);
    }
    __syncthreads();

    // convres_2: 1x128
    if (tid < 128) {
        int o = tid;
        const float* wr = wT + WT_C2_2;
        float s = W.c2b2[o];
#pragma unroll 4
        for (int i = 0; i < 128; ++i)
#pragma unroll
            for (int j = 0; j < 3; ++j)
                s = fmaf(wr[(i * 3 + j) * 128 + o], a2[(4 * j) * 128 + i], s);
        s = fmaxf(s, 0.f);
        const float* dr = wT + WT_DW2;
        float rs = W.db2[o];
#pragma unroll 4
        for (int i = 0; i < 64; ++i)
            rs = fmaf(dr[i * 128 + o], o1[16 * 64 + i], rs);
        y[(size_t)b * 128 + o] = fmaxf(s + rs, 0.f);
    }
}

// ---------------------------------------------------------------------------
// K2: Laplace + 32 leading TCN blocks hidden in its shadow.
// R11: Q=4 queries per wave (R4 had 2). Diagnosis after R4/R8/R9 converged
// at ~95us: the limiter is the CU-shared LDS-read pipe (8 ds_read_b128 per
// sub feed only 64 FMA at Q=2 -> ds pipe 3x oversubscribed, ~41us). Q=4
// doubles FMAs per ds_read and HALVES blocks (2048) -> total ds_read
// instruction count halves. Live set ~230 regs fits the 256-VGPR cap from
// __launch_bounds__(256,2); R4-level occupancy (8 waves/CU) was proven
// sufficient (R5/R8/R10 occupancy increases were all null).
// Per-query keys, sort, pop order bit-identical to R4.
// ---------------------------------------------------------------------------
#define STILE 128
#define SPAD  36
#define TCN_BLOCKS 32
#define NTILE (T_ / STILE)   // 8
#define LAP_BLOCKS ((B_ * T_) / 16)   // 2048 (16 queries per block)

__global__ __launch_bounds__(256, 2) void k_laplace(
    const float* __restrict__ h, const float* __restrict__ sq,
    float* __restrict__ acc, TcnW tw, const float* __restrict__ wT,
    float* __restrict__ y)
{
    __shared__ float tile[2][STILE * SPAD];   // 36864 B double buffer
    __shared__ float wacc[4 * 32];
    __shared__ float qbuf[16 * 32];

    if (blockIdx.x < TCN_BLOCKS) {
        tcn_block(blockIdx.x, tw, wT, &tile[0][0], y, threadIdx.x);
        return;
    }
    const int bid = blockIdx.x - TCN_BLOCKS;

    const int tid = threadIdx.x;
    const int wv  = tid >> 6;          // 0..3
    const int ln  = tid & 63;
    const int b   = bid >> 6;          // 64 blocks per batch
    const int t0  = (bid & 63) * 16;
    const int tA  = t0 + wv * 4;
    const int tB  = tA + 1;
    const int tC  = tA + 2;
    const int tD  = tA + 3;

    const float* hb  = h  + (size_t)b * T_ * LH_;
    const float* sqb = sq + b * T_;

    if (ln < 32) {
        qbuf[(wv * 4 + 0) * 32 + ln] = hb[tA * LH_ + ln];
        qbuf[(wv * 4 + 1) * 32 + ln] = hb[tB * LH_ + ln];
        qbuf[(wv * 4 + 2) * 32 + ln] = hb[tC * LH_ + ln];
        qbuf[(wv * 4 + 3) * 32 + ln] = hb[tD * LH_ + ln];
    }
    float qA[32], qB[32], qC[32], qD[32];
#pragma unroll
    for (int i4 = 0; i4 < 8; ++i4) {
        float4 a4 = *(const float4*)(hb + (size_t)tA * LH_ + i4 * 4);
        float4 b4 = *(const float4*)(hb + (size_t)tB * LH_ + i4 * 4);
        float4 c4 = *(const float4*)(hb + (size_t)tC * LH_ + i4 * 4);
        float4 d4 = *(const float4*)(hb + (size_t)tD * LH_ + i4 * 4);
        qA[i4 * 4 + 0] = a4.x; qA[i4 * 4 + 1] = a4.y; qA[i4 * 4 + 2] = a4.z; qA[i4 * 4 + 3] = a4.w;
        qB[i4 * 4 + 0] = b4.x; qB[i4 * 4 + 1] = b4.y; qB[i4 * 4 + 2] = b4.z; qB[i4 * 4 + 3] = b4.w;
        qC[i4 * 4 + 0] = c4.x; qC[i4 * 4 + 1] = c4.y; qC[i4 * 4 + 2] = c4.z; qC[i4 * 4 + 3] = c4.w;
        qD[i4 * 4 + 0] = d4.x; qD[i4 * 4 + 1] = d4.y; qD[i4 * 4 + 2] = d4.z; qD[i4 * 4 + 3] = d4.w;
    }
    const float sqA = sqb[tA], sqB = sqb[tB], sqC = sqb[tC], sqD = sqb[tD];

    const int st_r  = tid >> 3, st_c4 = tid & 7;
    auto stage = [&](int buf, int s_base) {
#pragma unroll
        for (int u = 0; u < 4; ++u) {
            int r = st_r + u * 32;
            float4 val = *(const float4*)(hb + (size_t)(s_base + r) * LH_ + st_c4 * 4);
            *(float4*)&tile[buf][r * SPAD + st_c4 * 4] = val;
        }
    };

    unsigned kA[16], kB[16], kC[16], kD[16];

    stage(0, 0);
    __syncthreads();

#pragma unroll
    for (int tl = 0; tl < NTILE; ++tl) {
        const int s_base = tl * STILE;
        const int cur = tl & 1;
        if (tl + 1 < NTILE) stage(cur ^ 1, s_base + STILE);
#pragma unroll
        for (int sub = 0; sub < 2; ++sub) {
            const int sr = sub * 64 + ln;
            const int s  = s_base + sr;
            const float* hs = &tile[cur][sr * SPAD];
            float dA = 0.f, dB = 0.f, dC = 0.f, dD = 0.f;
#pragma unroll
            for (int q4 = 0; q4 < 8; ++q4) {
                float4 hv4 = *(const float4*)(hs + q4 * 4);
                dA = fmaf(hv4.x, qA[q4 * 4 + 0], dA); dB = fmaf(hv4.x, qB[q4 * 4 + 0], dB);
                dC = fmaf(hv4.x, qC[q4 * 4 + 0], dC); dD = fmaf(hv4.x, qD[q4 * 4 + 0], dD);
                dA = fmaf(hv4.y, qA[q4 * 4 + 1], dA); dB = fmaf(hv4.y, qB[q4 * 4 + 1], dB);
                dC = fmaf(hv4.y, qC[q4 * 4 + 1], dC); dD = fmaf(hv4.y, qD[q4 * 4 + 1], dD);
                dA = fmaf(hv4.z, qA[q4 * 4 + 2], dA); dB = fmaf(hv4.z, qB[q4 * 4 + 2], dB);
                dC = fmaf(hv4.z, qC[q4 * 4 + 2], dC); dD = fmaf(hv4.z, qD[q4 * 4 + 2], dD);
                dA = fmaf(hv4.w, qA[q4 * 4 + 3], dA); dB = fmaf(hv4.w, qB[q4 * 4 + 3], dB);
                dC = fmaf(hv4.w, qC[q4 * 4 + 3], dC); dD = fmaf(hv4.w, qD[q4 * 4 + 3], dD);
            }
            const float sqs = sqb[s];
            float d2A = fmaxf(sqA + sqs - 2.f * dA, 0.f);
            float d2B = fmaxf(sqB + sqs - 2.f * dB, 0.f);
            float d2C = fmaxf(sqC + sqs - 2.f * dC, 0.f);
            float d2D = fmaxf(sqD + sqs - 2.f * dD, 0.f);
            unsigned keyA = (__float_as_uint(d2A) & 0xFFFFFC00u) | (unsigned)s;
            unsigned keyB = (__float_as_uint(d2B) & 0xFFFFFC00u) | (unsigned)s;
            unsigned keyC = (__float_as_uint(d2C) & 0xFFFFFC00u) | (unsigned)s;
            unsigned keyD = (__float_as_uint(d2D) & 0xFFFFFC00u) | (unsigned)s;
            if (s == tA) keyA = 0xFFFFFC00u | (unsigned)s;
            if (s == tB) keyB = 0xFFFFFC00u | (unsigned)s;
            if (s == tC) keyC = 0xFFFFFC00u | (unsigned)s;
            if (s == tD) keyD = 0xFFFFFC00u | (unsigned)s;
            kA[tl * 2 + sub] = keyA;
            kB[tl * 2 + sub] = keyB;
            kC[tl * 2 + sub] = keyC;
            kD[tl * 2 + sub] = keyD;
        }
        __syncthreads();   // staging of nxt done; cur free for reuse next iter
    }

    float racc = 0.f;

    auto process = [&](unsigned (&ku)[16], int qslot) {
        // ---- per-lane bitonic sort, ascending (static indices) ----
#pragma unroll
        for (int k = 2; k <= 16; k <<= 1) {
#pragma unroll
            for (int j = k >> 1; j > 0; j >>= 1) {
#pragma unroll
                for (int i = 0; i < 16; ++i) {
                    int l = i ^ j;
                    if (l > i) {
                        unsigned a = ku[i], bb = ku[l];
                        unsigned mn = min(a, bb), mx = max(a, bb);
                        bool up = ((i & k) == 0);
                        ku[i] = up ? mn : mx;
                        ku[l] = up ? mx : mn;
                    }
                }
            }
        }
        // ---- pop-head extraction: K rounds; shift depth 11 sufficient ----
        int   sk[K_];
        float wk[K_];
#pragma unroll
        for (int r = 0; r < K_; ++r) {
            unsigned mu = wave_min_u32(ku[0]);
            int s_win = (int)(mu & 1023u);
            sk[r] = s_win;
            wk[r] = __expf(-0.5f * __uint_as_float(mu & 0xFFFFFC00u));
            const bool winlane = ((s_win & 63) == ln);
#pragma unroll
            for (int i = 0; i < 10; ++i)
                ku[i] = winlane ? ku[i + 1] : ku[i];
            ku[10] = winlane ? 0xFFFFFFFFu : ku[10];
        }
        const int i = ln & 31;
        const float qi = qbuf[qslot * 32 + i];
        float W = 0.f, sm = 0.f;
#pragma unroll
        for (int k = 0; k < K_; ++k) {
            W += wk[k];
            sm = fmaf(wk[k], hb[(size_t)sk[k] * LH_ + i], sm);
        }
        sm *= __builtin_amdgcn_rcpf(W + 1e-8f);
        float z  = qi - sm;
        float ex = __expf(2.f * z);
        racc += 1.f - 2.f * __builtin_amdgcn_rcpf(ex + 1.f);
    };

    process(kA, wv * 4 + 0);
    process(kB, wv * 4 + 1);
    process(kC, wv * 4 + 2);
    process(kD, wv * 4 + 3);

    if (ln < 32) wacc[wv * 32 + ln] = racc;
    __syncthreads();
    if (tid < 32) {
        float tot = wacc[tid] + wacc[32 + tid] + wacc[64 + tid] + wacc[96 + tid];
        atomicAdd(&acc[b * LH_ + tid], tot);
    }
}

// ---------------------------------------------------------------------------
// K3: head (unchanged, proven)
// ---------------------------------------------------------------------------
struct HeadW {
    const float *ow, *ob, *head_w, *head_b;
    const float *f1w, *f1b, *f2w, *f2b, *r1w, *r1b, *r2w, *r2b;
};

__global__ __launch_bounds__(256) void k_head(
    const float* __restrict__ y, const float* __restrict__ acc,
    HeadW hw, float* __restrict__ out)
{
    const int b = blockIdx.x, tid = threadIdx.x;
    __shared__ float yv[128], v96[96], h1[256], h2[256], h3[128];

    if (tid < 128) yv[tid] = y[b * 128 + tid];
    else if (tid < 160) {
        int j = tid - 128;
        float s = hw.ob[j];
        for (int i = 0; i < 32; ++i)
            s = fmaf(acc[b * 32 + i] * (1.f / 1024.f), hw.ow[i * 32 + j], s);
        v96[j] = s;
    }
    __syncthreads();
    if (tid < 64) {
        float s = hw.head_b[tid];
        for (int i = 0; i < 128; ++i)
            s = fmaf(yv[i], hw.head_w[i * 64 + tid], s);
        v96[32 + tid] = s;
    }
    __syncthreads();
    {
        float s = hw.f1b[tid];
        for (int i = 0; i < 96; ++i)
            s = fmaf(v96[i], hw.f1w[i * 256 + tid], s);
        h1[tid] = fmaxf(s, 0.f);
    }
    __syncthreads();
    {
        float s = hw.f2b[tid];
        for (int i = 0; i < 256; ++i)
            s = fmaf(h1[i], hw.f2w[i * 256 + tid], s);
        h2[tid] = fmaxf(s, 0.f);
    }
    __syncthreads();
    if (tid < 128) {
        float s = hw.r1b[tid];
        for (int i = 0; i < 256; ++i)
            s = fmaf(h2[i], hw.r1w[i * 128 + tid], s);
        h3[tid] = fmaxf(s, 0.f);
    }
    __syncthreads();
    if (tid < 10) {
        float s = hw.r2b[tid];
        for (int i = 0; i < 128; ++i)
            s = fmaf(h3[i], hw.r2w[i * 10 + tid], s);
        out[b * 10 + tid] = s;
    }
}

// ---------------------------------------------------------------------------
extern "C" void kernel_launch(void* const* d_in, const int* in_sizes, int n_in,
                              void* d_out, int out_size, void* d_ws, size_t ws_size,
                              hipStream_t stream)
{
    const float* x  = (const float*)d_in[0];
    const float* pw = (const float*)d_in[1];
    const float* pb = (const float*)d_in[2];

    const float* c1w0 = (const float*)d_in[5];  const float* c1b0 = (const float*)d_in[6];
    const float* c2w0 = (const float*)d_in[7];  const float* c2b0 = (const float*)d_in[8];
    const float* dw0  = (const float*)d_in[9];  const float* db0  = (const float*)d_in[10];
    const float* c1w1 = (const float*)d_in[11]; const float* c1b1 = (const float*)d_in[12];
    const float* c2w1 = (const float*)d_in[13]; const float* c2b1 = (const float*)d_in[14];
    const float* dw1  = (const float*)d_in[15]; const float* db1  = (const float*)d_in[16];
    const float* c1w2 = (const float*)d_in[17]; const float* c1b2 = (const float*)d_in[18];
    const float* c2w2 = (const float*)d_in[19]; const float* c2b2 = (const float*)d_in[20];
    const float* dw2  = (const float*)d_in[21]; const float* db2  = (const float*)d_in[22];

    TcnW tw;
    tw.x    = x;
    tw.c1b0 = c1b0; tw.c2b0 = c2b0; tw.db0 = db0;
    tw.c1b1 = c1b1; tw.c2b1 = c2b1; tw.db1 = db1;
    tw.c1b2 = c1b2; tw.c2b2 = c2b2; tw.db2 = db2;

    HeadW hw = { (const float*)d_in[3],  (const float*)d_in[4],
                 (const float*)d_in[23], (const float*)d_in[24],
                 (const float*)d_in[25], (const float*)d_in[26],
                 (const float*)d_in[27], (const float*)d_in[28],
                 (const float*)d_in[29], (const float*)d_in[30],
                 (const float*)d_in[31], (const float*)d_in[32] };

    float* W   = (float*)d_ws;
    float* h   = W + WS_H;
    float* sq  = W + WS_SQ;
    float* acc = W + WS_ACC;
    float* wT  = W + WS_WT;
    float* y   = W + WS_Y;

    WSegs S;
    const float* srcs[9] = {c1w0, c2w0, dw0, c1w1, c2w1, dw1, c1w2, c2w2, dw2};
    const int k3s[9]   = {24, 96, 8, 96, 192, 32, 192, 384, 64};
    const int col2[9]  = {5, 5, 5, 6, 6, 6, 7, 7, 7};
    const int offs[10] = {WT_C1_0, WT_C2_0, WT_DW0, WT_C1_1, WT_C2_1, WT_DW1,
                          WT_C1_2, WT_C2_2, WT_DW2, WT_TOTAL};
    for (int i = 0; i < 9; ++i) { S.src[i] = srcs[i]; S.k3[i] = k3s[i]; S.colog2[i] = col2[i]; }
    for (int i = 0; i < 10; ++i) S.off[i] = offs[i];

    k_project<<<PROJ_BLOCKS + WT_BLOCKS, 256, 0, stream>>>(x, pw, pb, h, sq, acc, S, wT);
    k_laplace<<<LAP_BLOCKS + TCN_BLOCKS, 256, 0, stream>>>(h, sq, acc, tw, wT, y);
    k_head<<<B_, 256, 0, stream>>>(y, acc, hw, (float*)d_out);
}